// Round 1
// baseline (376.991 us; speedup 1.0000x reference)
//
#include <hip/hip_runtime.h>

#define NBINS 256
#define HWPIX (512 * 512)      // pixels per channel
#define NCHAN (64 * 3)         // N*C channels
#define HIST_BPC 8             // blocks per channel, histogram pass
#define APPLY_BPC 16           // blocks per channel, apply pass

// Zero the per-channel histograms in workspace (harness poisons ws with 0xAA).
__global__ void zero_hist(int* __restrict__ hist) {
    hist[blockIdx.x * blockDim.x + threadIdx.x] = 0;
}

// Pass 1: per-channel 256-bin histogram. 4 per-wave LDS sub-histograms to cut
// LDS atomic contention; one global atomicAdd per (block, bin).
__global__ __launch_bounds__(256) void hist_kernel(const float* __restrict__ x,
                                                   int* __restrict__ hist) {
    __shared__ int lh[4][NBINS];
    const int chan = blockIdx.x / HIST_BPC;
    const int blk  = blockIdx.x % HIST_BPC;
    const int tid  = threadIdx.x;
    const int wave = tid >> 6;

    for (int i = tid; i < 4 * NBINS; i += 256) ((int*)lh)[i] = 0;
    __syncthreads();

    const float4* base = (const float4*)x + (size_t)chan * (HWPIX / 4);
    const int vecPerBlock = HWPIX / 4 / HIST_BPC;  // 8192
    const int start = blk * vecPerBlock;
    int* myh = lh[wave];

    for (int i = tid; i < vecPerBlock; i += 256) {
        float4 v = base[start + i];
        atomicAdd(&myh[(int)fminf(fmaxf(v.x, 0.f), 255.f)], 1);
        atomicAdd(&myh[(int)fminf(fmaxf(v.y, 0.f), 255.f)], 1);
        atomicAdd(&myh[(int)fminf(fmaxf(v.z, 0.f), 255.f)], 1);
        atomicAdd(&myh[(int)fminf(fmaxf(v.w, 0.f), 255.f)], 1);
    }
    __syncthreads();

    int s = lh[0][tid] + lh[1][tid] + lh[2][tid] + lh[3][tid];
    if (s) atomicAdd(&hist[chan * NBINS + tid], s);
}

// Pass 2: each block recomputes its channel's LUT from the global histogram
// (256-thread Hillis-Steele inclusive scan in LDS — exact int arithmetic,
// identical to the fp32 reference since all values < 2^24), then applies it.
__global__ __launch_bounds__(256) void apply_kernel(const float* __restrict__ x,
                                                    float* __restrict__ out,
                                                    const int* __restrict__ hist) {
    __shared__ int scan[NBINS];
    __shared__ float slut[NBINS];
    __shared__ int s_last_idx;
    __shared__ int s_last;

    const int chan = blockIdx.x / APPLY_BPC;
    const int blk  = blockIdx.x % APPLY_BPC;
    const int tid  = threadIdx.x;

    const int h = hist[chan * NBINS + tid];
    scan[tid] = h;
    if (tid == 0) s_last_idx = 0;
    __syncthreads();
    if (h > 0) atomicMax(&s_last_idx, tid);

    // inclusive scan over 256 bins
    for (int off = 1; off < NBINS; off <<= 1) {
        __syncthreads();
        int t = (tid >= off) ? scan[tid - off] : 0;
        __syncthreads();
        scan[tid] += t;
    }
    __syncthreads();
    if (tid == s_last_idx) s_last = h;  // count of last nonzero bin
    __syncthreads();

    const int total = scan[NBINS - 1];
    const int step  = (total - s_last) / 255;  // floor, nonneg

    float lutv;
    if (step == 0) {
        lutv = (float)tid;                      // identity mapping
    } else if (tid == 0) {
        lutv = 0.f;                             // shifted-in leading zero
    } else {
        int l = (scan[tid - 1] + (step >> 1)) / step;
        lutv = (float)(l < 255 ? l : 255);
    }
    slut[tid] = lutv;
    __syncthreads();

    const float4* bx = (const float4*)x + (size_t)chan * (HWPIX / 4);
    float4*       bo = (float4*)out + (size_t)chan * (HWPIX / 4);
    const int vecPerBlock = HWPIX / 4 / APPLY_BPC;  // 4096
    const int start = blk * vecPerBlock;

    for (int i = tid; i < vecPerBlock; i += 256) {
        float4 v = bx[start + i];
        float4 o;
        o.x = slut[(int)fminf(fmaxf(v.x, 0.f), 255.f)];
        o.y = slut[(int)fminf(fmaxf(v.y, 0.f), 255.f)];
        o.z = slut[(int)fminf(fmaxf(v.z, 0.f), 255.f)];
        o.w = slut[(int)fminf(fmaxf(v.w, 0.f), 255.f)];
        bo[start + i] = o;
    }
}

extern "C" void kernel_launch(void* const* d_in, const int* in_sizes, int n_in,
                              void* d_out, int out_size, void* d_ws, size_t ws_size,
                              hipStream_t stream) {
    const float* x = (const float*)d_in[0];
    // d_in[1] is `magnitude` — unused by the reference.
    float* out = (float*)d_out;
    int* hist = (int*)d_ws;  // NCHAN * NBINS int32 = 192 KiB

    zero_hist<<<NCHAN, NBINS, 0, stream>>>(hist);
    hist_kernel<<<NCHAN * HIST_BPC, 256, 0, stream>>>(x, hist);
    apply_kernel<<<NCHAN * APPLY_BPC, 256, 0, stream>>>(x, out, hist);
}